// Round 10
// baseline (1214.512 us; speedup 1.0000x reference)
//
#include <hip/hip_runtime.h>
#include <hip/hip_bf16.h>

#define NC 80
#define NK 51
#define REG_MAX 16
#define MAX_DET 100
#define A_TOT 8400
#define BS 16

// out layout (float32): num[16] | boxes[16*100*4] | scores[16*100] | classes[16*100] | kpts[16*100*17*3]
#define OUT_NUM 0
#define OUT_BOX 16
#define OUT_SCORE (16 + 16*MAX_DET*4)
#define OUT_CLASS (OUT_SCORE + 16*MAX_DET)
#define OUT_KPT (OUT_CLASS + 16*MAX_DET)

static __device__ __forceinline__ unsigned long long mk_key(unsigned u, int a) {
    return ((unsigned long long)u << 32) | (unsigned)(0x7FFFFFFF - a);
}

// -------- Kernel 1 v9: v6 per-lane tile + v7 pipelining, 256 threads --------
// v7/v8 post-mortem: 512-thread blocks get hard-capped at 128 VGPR by hipcc
// (both launch_bounds variants) -> acc spill -> 2.5GB scratch. v6's
// 256-thread per-lane tile allocated cleanly (124 VGPR, no spill); its
// failure was unprefetched feature loads (VALUBusy 24%). This kernel = v6
// structure + v7's explicit pipeline:
//  - 4 waves; lane=(og=lane>>3, slot=lane&7); wave covers all NOC ocs x
//    64 anchors; block = 256 anchors.
//  - weights: per-lane-distinct ds_read_b128 from double-buffered LDS
//    (row stride 36 floats: O=10 -> 2-way alias (free), O=5 -> fully
//    conflict-free). 10 reads vs 320 FMA per group -> LDS duty 0.75.
//  - features: double-banked fb0/fb1, bank = static c4&1 in the fully
//    unrolled 8-group loop (rule-20 safe); prefetch issued one group
//    (~1280cy at 2 waves/SIMD) ahead of consumption.
//  - L2 (C=512) split into 2 oc-halves (O=5, serial path == L1 block);
//    topk merges halves (tie -> lower half = first-max; verified in v7).
// Per-(oc,anchor) chain: bias then strictly ascending channel fmaf ->
// bit-identical to all prior rounds.
template<int C, int A, int O>
static __device__ __forceinline__ void score_tile(
    const float* __restrict__ x, const float* __restrict__ w,
    const float* __restrict__ bias,
    int b, int a0, int oc_base,
    float* __restrict__ out_m, int* __restrict__ out_i,
    float* __restrict__ wsh)
{
    constexpr int NOC = 8 * O;       // ocs per block (80 or 40)
    constexpr int NCH = C / 32;      // weight chunks
    constexpr int NF4 = NOC * 8;     // float4 per weight chunk

    int t = threadIdx.x;
    int lane = t & 63;
    int wv = t >> 6;
    int og = lane >> 3;
    int slot = lane & 7;
    int oc0 = oc_base + og * O;      // this lane's first (global) oc

    int base = a0 + wv * 64 + slot * 8;   // nominal anchors (writes guarded)
    int aa = base;
    if (aa > A - 8) aa = A - 8;           // ragged tail: duplicate reads
    const float* xb = x + (long)b * C * A + aa;

    float acc[O][8];
#pragma unroll
    for (int j = 0; j < O; ++j) {
        float bv = bias[oc0 + j];
#pragma unroll
        for (int q = 0; q < 8; ++q) acc[j][q] = bv;
    }

    // weight staging: NF4 float4 per chunk, 256 threads -> up to 3 each
    int i0 = t, i1 = t + 256, i2 = t + 512;
    bool s1v = (i1 < NF4), s2v = (i2 < NF4);
    int o0 = i0 >> 3, q0 = i0 & 7;
    int o1 = i1 >> 3, q1 = i1 & 7;
    int o2 = i2 >> 3, q2 = i2 & 7;

    // prologue: issue chunk-0 weight loads + group-0 feature loads
    float4 s0, s1, s2;
    s0 = *(const float4*)(w + (long)(oc_base + o0) * C + q0 * 4);
    if (s1v) s1 = *(const float4*)(w + (long)(oc_base + o1) * C + q1 * 4);
    if (s2v) s2 = *(const float4*)(w + (long)(oc_base + o2) * C + q2 * 4);

    float4 fb0[8], fb1[8];           // [cc*2 + half]; static-indexed only
#pragma unroll
    for (int cc = 0; cc < 4; ++cc) {
        fb0[cc * 2]     = *(const float4*)(xb + (long)cc * A);
        fb0[cc * 2 + 1] = *(const float4*)(xb + (long)cc * A + 4);
    }
    const float* fnext = xb + 4 * (long)A;

    *(float4*)&wsh[o0 * 36 + q0 * 4] = s0;
    if (s1v) *(float4*)&wsh[o1 * 36 + q1 * 4] = s1;
    if (s2v) *(float4*)&wsh[o2 * 36 + q2 * 4] = s2;
    __syncthreads();

    // per-group compute macro: 10(O) per-lane b128 weight reads + O*32 FMA
#define V9_COMPUTE(FARR)                                                    \
    {                                                                       \
        _Pragma("unroll")                                                   \
        for (int j = 0; j < O; ++j) {                                       \
            float4 w4 = *(const float4*)(wp + j * 36 + c4 * 4);             \
            float wc0 = w4.x, wc1 = w4.y, wc2 = w4.z, wc3 = w4.w;           \
            float4 f0l = FARR[0], f0h = FARR[1];                            \
            float4 f1l = FARR[2], f1h = FARR[3];                            \
            float4 f2l = FARR[4], f2h = FARR[5];                            \
            float4 f3l = FARR[6], f3h = FARR[7];                            \
            acc[j][0] = fmaf(wc0, f0l.x, acc[j][0]);                        \
            acc[j][1] = fmaf(wc0, f0l.y, acc[j][1]);                        \
            acc[j][2] = fmaf(wc0, f0l.z, acc[j][2]);                        \
            acc[j][3] = fmaf(wc0, f0l.w, acc[j][3]);                        \
            acc[j][4] = fmaf(wc0, f0h.x, acc[j][4]);                        \
            acc[j][5] = fmaf(wc0, f0h.y, acc[j][5]);                        \
            acc[j][6] = fmaf(wc0, f0h.z, acc[j][6]);                        \
            acc[j][7] = fmaf(wc0, f0h.w, acc[j][7]);                        \
            acc[j][0] = fmaf(wc1, f1l.x, acc[j][0]);                        \
            acc[j][1] = fmaf(wc1, f1l.y, acc[j][1]);                        \
            acc[j][2] = fmaf(wc1, f1l.z, acc[j][2]);                        \
            acc[j][3] = fmaf(wc1, f1l.w, acc[j][3]);                        \
            acc[j][4] = fmaf(wc1, f1h.x, acc[j][4]);                        \
            acc[j][5] = fmaf(wc1, f1h.y, acc[j][5]);                        \
            acc[j][6] = fmaf(wc1, f1h.z, acc[j][6]);                        \
            acc[j][7] = fmaf(wc1, f1h.w, acc[j][7]);                        \
            acc[j][0] = fmaf(wc2, f2l.x, acc[j][0]);                        \
            acc[j][1] = fmaf(wc2, f2l.y, acc[j][1]);                        \
            acc[j][2] = fmaf(wc2, f2l.z, acc[j][2]);                        \
            acc[j][3] = fmaf(wc2, f2l.w, acc[j][3]);                        \
            acc[j][4] = fmaf(wc2, f2h.x, acc[j][4]);                        \
            acc[j][5] = fmaf(wc2, f2h.y, acc[j][5]);                        \
            acc[j][6] = fmaf(wc2, f2h.z, acc[j][6]);                        \
            acc[j][7] = fmaf(wc2, f2h.w, acc[j][7]);                        \
            acc[j][0] = fmaf(wc3, f3l.x, acc[j][0]);                        \
            acc[j][1] = fmaf(wc3, f3l.y, acc[j][1]);                        \
            acc[j][2] = fmaf(wc3, f3l.z, acc[j][2]);                        \
            acc[j][3] = fmaf(wc3, f3l.w, acc[j][3]);                        \
            acc[j][4] = fmaf(wc3, f3h.x, acc[j][4]);                        \
            acc[j][5] = fmaf(wc3, f3h.y, acc[j][5]);                        \
            acc[j][6] = fmaf(wc3, f3h.z, acc[j][6]);                        \
            acc[j][7] = fmaf(wc3, f3h.w, acc[j][7]);                        \
        }                                                                   \
    }

#define V9_PREFETCH(FARR)                                                   \
    {                                                                       \
        _Pragma("unroll")                                                   \
        for (int cc = 0; cc < 4; ++cc) {                                    \
            FARR[cc * 2]     = *(const float4*)(fnext + (long)cc * A);      \
            FARR[cc * 2 + 1] = *(const float4*)(fnext + (long)cc * A + 4);  \
        }                                                                   \
        fnext += 4 * (long)A;                                               \
    }

    for (int kc = 0; kc < NCH; ++kc) {
        if (kc + 1 < NCH) {          // issue next chunk's weight loads now
            const float* wn = w + (long)(kc + 1) * 32;
            s0 = *(const float4*)(wn + (long)(oc_base + o0) * C + q0 * 4);
            if (s1v) s1 = *(const float4*)(wn + (long)(oc_base + o1) * C + q1 * 4);
            if (s2v) s2 = *(const float4*)(wn + (long)(oc_base + o2) * C + q2 * 4);
        }
        const float* wp = wsh + (kc & 1) * (NOC * 36) + (og * O) * 36;
#pragma unroll
        for (int c4 = 0; c4 < 8; ++c4) {
            // prefetch next group's features into the other (static) bank
            if (c4 < 7 || kc + 1 < NCH) {
                if ((c4 & 1) == 0) { V9_PREFETCH(fb1) } else { V9_PREFETCH(fb0) }
            }
            if ((c4 & 1) == 0) { V9_COMPUTE(fb0) } else { V9_COMPUTE(fb1) }
        }
        if (kc + 1 < NCH) {          // write staged weights, one barrier/chunk
            float* wd = wsh + ((kc & 1) ^ 1) * (NOC * 36);
            *(float4*)&wd[o0 * 36 + q0 * 4] = s0;
            if (s1v) *(float4*)&wd[o1 * 36 + q1 * 4] = s1;
            if (s2v) *(float4*)&wd[o2 * 36 + q2 * 4] = s2;
            __syncthreads();
        }
    }
#undef V9_COMPUTE
#undef V9_PREFETCH

    // per-lane argmax over own O ocs (first-max: ascending j, strict >)
    float m[8]; int id[8];
#pragma unroll
    for (int q = 0; q < 8; ++q) {
        float mm = acc[0][q]; int mi = 0;
#pragma unroll
        for (int j = 1; j < O; ++j)
            if (acc[j][q] > mm) { mm = acc[j][q]; mi = j; }
        m[q] = mm; id[q] = oc0 + mi;
    }

    // cross-og reduce via shfl_xor; ties -> lower og (first-max over oc)
#pragma unroll
    for (int mask = 8; mask <= 32; mask <<= 1) {
        bool other_first = (lane & mask) != 0;   // partner has lower oc range
#pragma unroll
        for (int q = 0; q < 8; ++q) {
            float om = __shfl_xor(m[q], mask, 64);
            int   oi = __shfl_xor(id[q], mask, 64);
            bool take = other_first ? (om >= m[q]) : (om > m[q]);
            if (take) { m[q] = om; id[q] = oi; }
        }
    }

    if (og == 0) {                   // lanes 0..7 (slot == lane) write
#pragma unroll
        for (int q = 0; q < 8; ++q) {
            int ga = base + q;       // nominal anchor; clamped lanes skip
            if (ga < A) {
                out_m[ga] = 1.0f / (1.0f + expf(-m[q]));
                out_i[ga] = id[q];
            }
        }
    }
}

__global__ __launch_bounds__(256, 2) void scores_fused(
    const float* __restrict__ x0, const float* __restrict__ x1, const float* __restrict__ x2,
    const float* __restrict__ w0, const float* __restrict__ w1, const float* __restrict__ w2,
    const float* __restrict__ bias0, const float* __restrict__ bias1, const float* __restrict__ bias2,
    float* __restrict__ max_s,       // [BS][A_TOT] (anchors <8000 here)
    int* __restrict__ cls_id,
    float* __restrict__ l2m,         // [2][BS][400] partial sigmoid-max
    int* __restrict__ l2i)           // [2][BS][400] partial argmax
{
    __shared__ float wsh[2 * 80 * 36];   // 23 KB double-buffered weights

    int bid = blockIdx.x;
    if (bid < 64) {                  // L2 first: 16 b x 2 tiles x 2 oc-halves
        int b = bid >> 2, rem = bid & 3;
        int tile = rem >> 1, h = rem & 1;
        score_tile<512, 400, 5>(x2, w2, bias2, b, tile * 256, h * 40,
            l2m + ((long)h * BS + b) * 400, l2i + ((long)h * BS + b) * 400, wsh);
    } else if (bid < 176) {          // L1: 16 b x 7 tiles of 256 (tile6 ragged)
        int r = bid - 64;
        int b = r / 7, tile = r - b * 7;
        score_tile<256, 1600, 10>(x1, w1, bias1, b, tile * 256, 0,
            max_s + (long)b * A_TOT + 6400, cls_id + (long)b * A_TOT + 6400, wsh);
    } else {                         // L0: 16 b x 25 tiles of 256
        int r = bid - 176;
        int b = r / 25, tile = r - b * 25;
        score_tile<128, 6400, 10>(x0, w0, bias0, b, tile * 256, 0,
            max_s + (long)b * A_TOT, cls_id + (long)b * A_TOT, wsh);
    }
}

// -------- Kernel 2: exact top-100 radix select (256 threads) + L2 merge --------
__global__ __launch_bounds__(256) void topk_kernel(
    float* __restrict__ max_s,       // [BS][A_TOT] (L2 region filled here)
    int* __restrict__ cls_id,
    const float* __restrict__ l2m, const int* __restrict__ l2i,
    float* __restrict__ out,
    int* __restrict__ top_idx)       // [BS][MAX_DET]
{
    int b = blockIdx.x;
    int t = threadIdx.x;
    int lane = t & 63;
    int wv = t >> 6;

    // merge L2 oc-halves (tie -> half A = lower ocs = first-max)
    for (int a = t; a < 400; a += 256) {
        float sA = l2m[(0 * BS + b) * 400 + a];
        float sB = l2m[(1 * BS + b) * 400 + a];
        int   iA = l2i[(0 * BS + b) * 400 + a];
        int   iB = l2i[(1 * BS + b) * 400 + a];
        bool ta = (sA >= sB);
        max_s[(long)b * A_TOT + 8000 + a] = ta ? sA : sB;
        cls_id[(long)b * A_TOT + 8000 + a] = ta ? iA : iB;
    }
    __syncthreads();

    __shared__ unsigned hist[4 * 256];
    __shared__ int tieIdx[A_TOT];
    __shared__ unsigned long long highKeys[128];
    __shared__ unsigned long long finalKeys[128];
    __shared__ int wmin[4];
    __shared__ unsigned s_prefix;
    __shared__ int s_k, s_nHigh, s_nTie, s_cnt, s_bcast;

    uint4 uu[9];
#pragma unroll
    for (int i = 0; i < 9; ++i) {
        int idx = t + i * 256;
        if (i < 8 || t < 52)
            uu[i] = *(const uint4*)((const unsigned*)(max_s + (long)b * A_TOT) + idx * 4);
        else
            uu[i] = make_uint4(0u, 0u, 0u, 0u);
    }

    if (t == 0) { s_prefix = 0; s_k = MAX_DET; s_nHigh = 0; s_nTie = 0; s_cnt = 0; }

    for (int pass = 0; pass < 4; ++pass) {
#pragma unroll
        for (int j = 0; j < 4; ++j) hist[t + j * 256] = 0;
        __syncthreads();

        unsigned pre = s_prefix;
        int k = s_k;
        int shHi = 32 - 8 * pass;
        int shD = 24 - 8 * pass;
#pragma unroll
        for (int i = 0; i < 9; ++i) {
            if (i < 8 || t < 52) {
                unsigned e[4] = { uu[i].x, uu[i].y, uu[i].z, uu[i].w };
#pragma unroll
                for (int j = 0; j < 4; ++j) {
                    bool cand = (pass == 0) ? true : ((e[j] >> shHi) == pre);
                    if (cand)
                        atomicAdd(&hist[(wv << 8) + ((e[j] >> shD) & 0xFF)], 1u);
                }
            }
        }
        __syncthreads();

        if (wv == 0) {
            unsigned c0 = 0, c1 = 0, c2 = 0, c3 = 0;
#pragma unroll
            for (int w = 0; w < 4; ++w) {
                const unsigned* hp = &hist[(w << 8) + lane * 4];
                c0 += hp[0]; c1 += hp[1]; c2 += hp[2]; c3 += hp[3];
            }
            unsigned s3 = c3, s2 = c2 + s3, s1 = c1 + s2, s0 = c0 + s1;
            unsigned tsum = s0;
#pragma unroll
            for (int off = 1; off < 64; off <<= 1) {
                unsigned o = __shfl_down(tsum, off, 64);
                if (lane + off < 64) tsum += o;
            }
            unsigned excl = tsum - s0;
            unsigned S0 = excl + s0, S1 = excl + s1, S2 = excl + s2, S3 = excl + s3;
            int ld = -1;
            unsigned uk = (unsigned)k;
            if (S3 >= uk)      ld = lane * 4 + 3;
            else if (S2 >= uk) ld = lane * 4 + 2;
            else if (S1 >= uk) ld = lane * 4 + 1;
            else if (S0 >= uk) ld = lane * 4 + 0;
            int d = ld;
#pragma unroll
            for (int off = 32; off > 0; off >>= 1) d = max(d, __shfl_xor(d, off, 64));
            int dn = d + 1;
            unsigned mine = 0;
            if (dn < 256 && lane == (dn >> 2)) {
                int e = dn & 3;
                mine = (e == 0) ? S0 : (e == 1) ? S1 : (e == 2) ? S2 : S3;
            }
#pragma unroll
            for (int off = 32; off > 0; off >>= 1) mine += __shfl_xor(mine, off, 64);
            if (lane == 0) {
                s_k = k - (int)mine;
                s_prefix = (pre << 8) | (unsigned)d;
            }
        }
        __syncthreads();
    }

    unsigned cut = s_prefix;
    int r = s_k;

#pragma unroll
    for (int i = 0; i < 9; ++i) {
        if (i < 8 || t < 52) {
            unsigned e[4] = { uu[i].x, uu[i].y, uu[i].z, uu[i].w };
#pragma unroll
            for (int j = 0; j < 4; ++j) {
                int a = (t + i * 256) * 4 + j;
                if (e[j] > cut) {
                    int p = atomicAdd(&s_nHigh, 1);
                    highKeys[p] = mk_key(e[j], a);
                } else if (e[j] == cut) {
                    int p = atomicAdd(&s_nTie, 1);
                    tieIdx[p] = a;
                }
            }
        }
    }
    __syncthreads();
    int m = s_nHigh;
    int nt = s_nTie;

    if (t < 128) finalKeys[t] = 0ull;
    __syncthreads();
    if (t < m) finalKeys[t] = highKeys[t];

    if (nt == r) {
        if (t < nt) finalKeys[m + t] = mk_key(cut, tieIdx[t]);
        __syncthreads();
    } else {
        __syncthreads();
        for (int j = 0; j < r; ++j) {
            int mn = 0x7FFFFFFF;
            for (int p = t; p < nt; p += 256) mn = min(mn, tieIdx[p]);
            for (int off = 32; off > 0; off >>= 1) mn = min(mn, __shfl_down(mn, off, 64));
            if (lane == 0) wmin[wv] = mn;
            __syncthreads();
            if (t == 0) {
                int v = min(min(wmin[0], wmin[1]), min(wmin[2], wmin[3]));
                s_bcast = v;
                finalKeys[m + j] = mk_key(cut, v);
            }
            __syncthreads();
            int v = s_bcast;
            for (int p = t; p < nt; p += 256)
                if (tieIdx[p] == v) tieIdx[p] = 0x7FFFFFFF;
            __syncthreads();
        }
    }

    for (int ksz = 2; ksz <= 128; ksz <<= 1) {
        for (int j = ksz >> 1; j > 0; j >>= 1) {
            if (t < 128) {
                int ixj = t ^ j;
                if (ixj > t) {
                    bool desc = ((t & ksz) == 0);
                    unsigned long long x = finalKeys[t], y = finalKeys[ixj];
                    bool sw = desc ? (x < y) : (x > y);
                    if (sw) { finalKeys[t] = y; finalKeys[ixj] = x; }
                }
            }
            __syncthreads();
        }
    }

    if (t < MAX_DET) {
        unsigned long long kk = finalKeys[t];
        float sc = __uint_as_float((unsigned)(kk >> 32));
        int a = 0x7FFFFFFF - (int)(kk & 0xFFFFFFFFull);
        out[OUT_SCORE + b * MAX_DET + t] = sc;
        out[OUT_CLASS + b * MAX_DET + t] = (float)cls_id[b * A_TOT + a];
        top_idx[b * MAX_DET + t] = a;
        if (sc > 0.25f) atomicAdd(&s_cnt, 1);
    }
    __syncthreads();
    if (t == 0) out[OUT_NUM + b] = (float)s_cnt;
}

// -------- Kernel 3: decode box + kpts for selected anchors (float4 dot) --------
__global__ __launch_bounds__(128) void decode_kernel(
    const float* __restrict__ x0, const float* __restrict__ x1, const float* __restrict__ x2,
    const float* __restrict__ w2_0, const float* __restrict__ b2_0,
    const float* __restrict__ w2_1, const float* __restrict__ b2_1,
    const float* __restrict__ w2_2, const float* __restrict__ b2_2,
    const float* __restrict__ w4_0, const float* __restrict__ b4_0,
    const float* __restrict__ w4_1, const float* __restrict__ b4_1,
    const float* __restrict__ w4_2, const float* __restrict__ b4_2,
    const int* __restrict__ top_idx,
    float* __restrict__ out)
{
    int b = blockIdx.y;
    int k = blockIdx.x;
    int a = top_idx[b * MAX_DET + k];

    const float* x; const float* w2; const float* bb2; const float* w4; const float* bb4;
    int C, A, W, a_local; float stride;
    if (a < 6400)      { x = x0; C = 128; A = 6400; W = 80; stride = 8.0f;  a_local = a;        w2 = w2_0; bb2 = b2_0; w4 = w4_0; bb4 = b4_0; }
    else if (a < 8000) { x = x1; C = 256; A = 1600; W = 40; stride = 16.0f; a_local = a - 6400; w2 = w2_1; bb2 = b2_1; w4 = w4_1; bb4 = b4_1; }
    else               { x = x2; C = 512; A = 400;  W = 20; stride = 32.0f; a_local = a - 8000; w2 = w2_2; bb2 = b2_2; w4 = w4_2; bb4 = b4_2; }

    __shared__ float fs[512];
    __shared__ float logits[64];
    __shared__ float kraw[NK];
    __shared__ float dist[4];

    int t = threadIdx.x;
    for (int c = t; c < C; c += 128)
        fs[c] = x[((long)b * C + c) * A + a_local];
    __syncthreads();

    if (t < 64 + NK) {
        const float* wrow; float acc;
        if (t < 64) { wrow = w2 + t * C; acc = bb2[t]; }
        else        { wrow = w4 + (t - 64) * C; acc = bb4[t - 64]; }
        for (int c = 0; c < C; c += 4) {
            float4 wv4 = *(const float4*)(wrow + c);
            float4 fv4 = *(const float4*)(&fs[c]);
            acc = fmaf(wv4.x, fv4.x, acc);
            acc = fmaf(wv4.y, fv4.y, acc);
            acc = fmaf(wv4.z, fv4.z, acc);
            acc = fmaf(wv4.w, fv4.w, acc);
        }
        if (t < 64) logits[t] = acc;
        else        kraw[t - 64] = acc;
    }
    __syncthreads();

    if (t < 4) {
        float mx = logits[t * 16];
#pragma unroll
        for (int r = 1; r < 16; ++r) mx = fmaxf(mx, logits[t * 16 + r]);
        float se = 0.0f, sw = 0.0f;
#pragma unroll
        for (int r = 0; r < 16; ++r) {
            float e = expf(logits[t * 16 + r] - mx);
            se += e; sw += e * (float)r;
        }
        dist[t] = sw / se;
    }
    __syncthreads();

    float ax = (float)(a_local % W) + 0.5f;
    float ay = (float)(a_local / W) + 0.5f;

    if (t == 0) {
        float x1c = ax - dist[0], y1c = ay - dist[1];
        float x2c = ax + dist[2], y2c = ay + dist[3];
        float* ob = out + OUT_BOX + ((long)b * MAX_DET + k) * 4;
        ob[0] = (x1c + x2c) * 0.5f * stride;
        ob[1] = (y1c + y2c) * 0.5f * stride;
        ob[2] = (x2c - x1c) * stride;
        ob[3] = (y2c - y1c) * stride;
    }
    if (t < 17) {
        float vx = kraw[t * 3], vy = kraw[t * 3 + 1], vv = kraw[t * 3 + 2];
        float gx = ax - 0.5f, gy = ay - 0.5f;
        float* ok = out + OUT_KPT + (((long)b * MAX_DET + k) * 17 + t) * 3;
        ok[0] = (vx * 2.0f + gx) * stride;
        ok[1] = (vy * 2.0f + gy) * stride;
        ok[2] = 1.0f / (1.0f + expf(-vv));
    }
}

extern "C" void kernel_launch(void* const* d_in, const int* in_sizes, int n_in,
                              void* d_out, int out_size, void* d_ws, size_t ws_size,
                              hipStream_t stream) {
    const float* x0 = (const float*)d_in[0];
    const float* x1 = (const float*)d_in[1];
    const float* x2 = (const float*)d_in[2];
    const float* w2[3] = {(const float*)d_in[3], (const float*)d_in[5], (const float*)d_in[7]};
    const float* b2[3] = {(const float*)d_in[4], (const float*)d_in[6], (const float*)d_in[8]};
    const float* w3[3] = {(const float*)d_in[9], (const float*)d_in[11], (const float*)d_in[13]};
    const float* b3[3] = {(const float*)d_in[10], (const float*)d_in[12], (const float*)d_in[14]};
    const float* w4[3] = {(const float*)d_in[15], (const float*)d_in[17], (const float*)d_in[19]};
    const float* b4[3] = {(const float*)d_in[16], (const float*)d_in[18], (const float*)d_in[20]};

    float* out = (float*)d_out;

    float* ws_maxs = (float*)d_ws;                     // [16][8400]
    int*   ws_cls  = (int*)(ws_maxs + BS * A_TOT);     // [16][8400]
    int*   ws_top  = (int*)(ws_cls + BS * A_TOT);      // [16][100]
    float* ws_l2m  = (float*)(ws_top + BS * MAX_DET);  // [2][16][400]
    int*   ws_l2i  = (int*)(ws_l2m + 2 * BS * 400);    // [2][16][400]

    // 64 (L2 halves) + 112 (L1) + 400 (L0) = 576 blocks of 256 threads
    scores_fused<<<dim3(576), 256, 0, stream>>>(
        x0, x1, x2, w3[0], w3[1], w3[2], b3[0], b3[1], b3[2],
        ws_maxs, ws_cls, ws_l2m, ws_l2i);
    topk_kernel<<<dim3(BS), 256, 0, stream>>>(ws_maxs, ws_cls, ws_l2m, ws_l2i, out, ws_top);
    decode_kernel<<<dim3(MAX_DET, BS), 128, 0, stream>>>(
        x0, x1, x2,
        w2[0], b2[0], w2[1], b2[1], w2[2], b2[2],
        w4[0], b4[0], w4[1], b4[1], w4[2], b4[2],
        ws_top, out);
}

// Round 11
// 311.360 us; speedup vs baseline: 3.9007x; 3.9007x over previous
//
#include <hip/hip_runtime.h>
#include <hip/hip_bf16.h>

#define NC 80
#define NK 51
#define REG_MAX 16
#define MAX_DET 100
#define A_TOT 8400
#define BS 16

// out layout (float32): num[16] | boxes[16*100*4] | scores[16*100] | classes[16*100] | kpts[16*100*17*3]
#define OUT_NUM 0
#define OUT_BOX 16
#define OUT_SCORE (16 + 16*MAX_DET*4)
#define OUT_CLASS (OUT_SCORE + 16*MAX_DET)
#define OUT_KPT (OUT_CLASS + 16*MAX_DET)

static __device__ __forceinline__ unsigned long long mk_key(unsigned u, int a) {
    return ((unsigned long long)u << 32) | (unsigned)(0x7FFFFFFF - a);
}

// -------- Kernel 1 v10: v1 structure at PP=4 with b128 feature reads --------
// Constraint learned from v7/v8/v9: hipcc pins this kernel family at 128
// VGPR and spills the rest (3x confirmed, 2.5GB scratch each) -> designs
// needing >~120 regs are dead. Within that: acc[20][4]=80 regs (PP=4).
// LDS arithmetic: v1 (PP=2) pays ~1150 LDS-cy per c4-group (20x4-wave
// weight-broadcast b128 ~960 + feature reads ~190) for 320 VALU-cy of
// work; PP=4 with ds_read_b128 features (4 consecutive anchors/lane)
// pays the SAME ~1150 for 640 -> same LDS-bound wall, half the time.
// Total LDS work ~27.8M cy / 256 CU ~ 45 us floor.
// Everything else is v1 verbatim: features [c][a] + weights [oc][c]
// staged in LDS, 2 barriers/chunk, 4 waves x 20 ocs, bias then strictly
// ascending channel fmaf chain (bit-identical), first-max argmax.
__global__ __launch_bounds__(256) void scores_fused(
    const float* __restrict__ x0, const float* __restrict__ x1, const float* __restrict__ x2,
    const float* __restrict__ w0, const float* __restrict__ w1, const float* __restrict__ w2,
    const float* __restrict__ bias0, const float* __restrict__ bias1, const float* __restrict__ bias2,
    float* __restrict__ max_s,       // [BS][A_TOT]
    int* __restrict__ cls_id)        // [BS][A_TOT]
{
    __shared__ float fs[32 * 256];   // 32 KB  [c][a] (256-anchor tile)
    __shared__ float wsh[80 * 32];   // 10 KB  [oc][c]
    __shared__ float rm[4][256];
    __shared__ int   ri[4][256];

    int bid = blockIdx.x;
    const float *x, *w, *bias; int C, A, a_off, b, tile;
    if (bid < 32) {                 // L2 first: longest serial work (16 chunks)
        x = x2; w = w2; bias = bias2; C = 512; A = 400; a_off = 8000;
        b = bid >> 1; tile = bid & 1;             // tile1 ragged (144 valid)
    } else if (bid < 144) {         // L1: 16 b x 7 tiles (tile6 ragged)
        int r = bid - 32;
        x = x1; w = w1; bias = bias1; C = 256; A = 1600; a_off = 6400;
        b = r / 7; tile = r - b * 7;
    } else {                        // L0: 16 b x 25 tiles (exact)
        int r = bid - 144;
        x = x0; w = w0; bias = bias0; C = 128; A = 6400; a_off = 0;
        b = r / 25; tile = r - b * 25;
    }
    int a0 = tile * 256;

    int t = threadIdx.x;
    int lane = t & 63;
    int wv = t >> 6;
    int oc0 = wv * 20;

    float acc[20][4];
#pragma unroll
    for (int j = 0; j < 20; ++j) {
        float bv = bias[oc0 + j];
        acc[j][0] = bv; acc[j][1] = bv; acc[j][2] = bv; acc[j][3] = bv;
    }

    const float* xb = x + (long)b * C * A;
    int nchunk = C >> 5;

    for (int kc = 0; kc < nchunk; ++kc) {
        __syncthreads();
        // stage features: 32 channels x 256 anchors = 2048 float4 (8/thread)
#pragma unroll
        for (int i = 0; i < 8; ++i) {
            int idx = t + i * 256;
            int c = idx >> 6;
            int q = (idx & 63) * 4;
            int aa = a0 + q; if (aa > A - 4) aa = A - 4;   // ragged: dup, writes guarded
            float4 v = *(const float4*)(xb + (long)(kc * 32 + c) * A + aa);
            *(float4*)(&fs[c * 256 + q]) = v;
        }
        // stage weights: 80 ocs x 32 channels = 640 float4
#pragma unroll
        for (int i = 0; i < 3; ++i) {
            int idx = t + i * 256;
            if (idx < 640) {
                int oc = idx >> 3;
                int q = (idx & 7) * 4;
                float4 v = *(const float4*)(w + oc * C + kc * 32 + q);
                *(float4*)(&wsh[oc * 32 + q]) = v;
            }
        }
        __syncthreads();

#pragma unroll 1
        for (int c4 = 0; c4 < 32; c4 += 4) {
            // 4 consecutive anchors per lane -> one ds_read_b128 per channel
            float4 f[4];
#pragma unroll
            for (int cc = 0; cc < 4; ++cc)
                f[cc] = *(const float4*)(&fs[(c4 + cc) * 256 + lane * 4]);
#pragma unroll
            for (int j = 0; j < 20; ++j) {
                float4 w4 = *(const float4*)(&wsh[(oc0 + j) * 32 + c4]);  // broadcast
                // ascending-channel chain per (oc, anchor) - bit-identical
                acc[j][0] = fmaf(w4.x, f[0].x, acc[j][0]);
                acc[j][0] = fmaf(w4.y, f[1].x, acc[j][0]);
                acc[j][0] = fmaf(w4.z, f[2].x, acc[j][0]);
                acc[j][0] = fmaf(w4.w, f[3].x, acc[j][0]);
                acc[j][1] = fmaf(w4.x, f[0].y, acc[j][1]);
                acc[j][1] = fmaf(w4.y, f[1].y, acc[j][1]);
                acc[j][1] = fmaf(w4.z, f[2].y, acc[j][1]);
                acc[j][1] = fmaf(w4.w, f[3].y, acc[j][1]);
                acc[j][2] = fmaf(w4.x, f[0].z, acc[j][2]);
                acc[j][2] = fmaf(w4.y, f[1].z, acc[j][2]);
                acc[j][2] = fmaf(w4.z, f[2].z, acc[j][2]);
                acc[j][2] = fmaf(w4.w, f[3].z, acc[j][2]);
                acc[j][3] = fmaf(w4.x, f[0].w, acc[j][3]);
                acc[j][3] = fmaf(w4.y, f[1].w, acc[j][3]);
                acc[j][3] = fmaf(w4.z, f[2].w, acc[j][3]);
                acc[j][3] = fmaf(w4.w, f[3].w, acc[j][3]);
            }
        }
    }

    // per-anchor argmax over this thread's 20 ocs (first-max semantics)
#pragma unroll
    for (int q = 0; q < 4; ++q) {
        float m = acc[0][q]; int mi = 0;
#pragma unroll
        for (int j = 1; j < 20; ++j)
            if (acc[j][q] > m) { m = acc[j][q]; mi = j; }
        rm[wv][lane * 4 + q] = m;
        ri[wv][lane * 4 + q] = oc0 + mi;
    }
    __syncthreads();

    // cross-wave reduce: ascending wv = ascending oc keeps first-max
    {
        float bm = rm[0][t]; int bi = ri[0][t];
#pragma unroll
        for (int v = 1; v < 4; ++v) {
            float om = rm[v][t];
            if (om > bm) { bm = om; bi = ri[v][t]; }
        }
        int ga = a0 + t;
        if (ga < A) {
            max_s[b * A_TOT + a_off + ga] = 1.0f / (1.0f + expf(-bm));
            cls_id[b * A_TOT + a_off + ga] = bi;
        }
    }
}

// -------- Kernel 2: exact top-100 radix select, 256 threads (round-6 version) --------
__global__ __launch_bounds__(256) void topk_kernel(
    const float* __restrict__ max_s, // [BS][A_TOT]
    const int* __restrict__ cls_id,  // [BS][A_TOT]
    float* __restrict__ out,
    int* __restrict__ top_idx)       // [BS][MAX_DET]
{
    int b = blockIdx.x;
    int t = threadIdx.x;
    int lane = t & 63;
    int wv = t >> 6;

    __shared__ unsigned hist[4 * 256];           // 4 KB per-wave histograms
    __shared__ int tieIdx[A_TOT];                // 33.6 KB (worst-case ties)
    __shared__ unsigned long long highKeys[128];
    __shared__ unsigned long long finalKeys[128];
    __shared__ int wmin[4];
    __shared__ unsigned s_prefix;
    __shared__ int s_k, s_nHigh, s_nTie, s_cnt, s_bcast;

    uint4 uu[9];
#pragma unroll
    for (int i = 0; i < 9; ++i) {
        int idx = t + i * 256;
        if (i < 8 || t < 52)
            uu[i] = *(const uint4*)((const unsigned*)(max_s + (long)b * A_TOT) + idx * 4);
        else
            uu[i] = make_uint4(0u, 0u, 0u, 0u);
    }

    if (t == 0) { s_prefix = 0; s_k = MAX_DET; s_nHigh = 0; s_nTie = 0; s_cnt = 0; }

    for (int pass = 0; pass < 4; ++pass) {
#pragma unroll
        for (int j = 0; j < 4; ++j) hist[t + j * 256] = 0;
        __syncthreads();                         // A: zeroed

        unsigned pre = s_prefix;
        int k = s_k;
        int shHi = 32 - 8 * pass;
        int shD = 24 - 8 * pass;
#pragma unroll
        for (int i = 0; i < 9; ++i) {
            if (i < 8 || t < 52) {
                unsigned e[4] = { uu[i].x, uu[i].y, uu[i].z, uu[i].w };
#pragma unroll
                for (int j = 0; j < 4; ++j) {
                    bool cand = (pass == 0) ? true : ((e[j] >> shHi) == pre);
                    if (cand)
                        atomicAdd(&hist[(wv << 8) + ((e[j] >> shD) & 0xFF)], 1u);
                }
            }
        }
        __syncthreads();                         // B: histograms complete

        if (wv == 0) {
            unsigned c0 = 0, c1 = 0, c2 = 0, c3 = 0;
#pragma unroll
            for (int w = 0; w < 4; ++w) {
                const unsigned* hp = &hist[(w << 8) + lane * 4];
                c0 += hp[0]; c1 += hp[1]; c2 += hp[2]; c3 += hp[3];
            }
            unsigned s3 = c3, s2 = c2 + s3, s1 = c1 + s2, s0 = c0 + s1;
            unsigned tsum = s0;
#pragma unroll
            for (int off = 1; off < 64; off <<= 1) {
                unsigned o = __shfl_down(tsum, off, 64);
                if (lane + off < 64) tsum += o;
            }
            unsigned excl = tsum - s0;
            unsigned S0 = excl + s0, S1 = excl + s1, S2 = excl + s2, S3 = excl + s3;
            int ld = -1;
            unsigned uk = (unsigned)k;
            if (S3 >= uk)      ld = lane * 4 + 3;
            else if (S2 >= uk) ld = lane * 4 + 2;
            else if (S1 >= uk) ld = lane * 4 + 1;
            else if (S0 >= uk) ld = lane * 4 + 0;
            int d = ld;
#pragma unroll
            for (int off = 32; off > 0; off >>= 1) d = max(d, __shfl_xor(d, off, 64));
            int dn = d + 1;
            unsigned mine = 0;
            if (dn < 256 && lane == (dn >> 2)) {
                int e = dn & 3;
                mine = (e == 0) ? S0 : (e == 1) ? S1 : (e == 2) ? S2 : S3;
            }
#pragma unroll
            for (int off = 32; off > 0; off >>= 1) mine += __shfl_xor(mine, off, 64);
            if (lane == 0) {
                s_k = k - (int)mine;
                s_prefix = (pre << 8) | (unsigned)d;
            }
        }
        __syncthreads();                         // C: cut update visible
    }

    unsigned cut = s_prefix;
    int r = s_k;

#pragma unroll
    for (int i = 0; i < 9; ++i) {
        if (i < 8 || t < 52) {
            unsigned e[4] = { uu[i].x, uu[i].y, uu[i].z, uu[i].w };
#pragma unroll
            for (int j = 0; j < 4; ++j) {
                int a = (t + i * 256) * 4 + j;
                if (e[j] > cut) {
                    int p = atomicAdd(&s_nHigh, 1);
                    highKeys[p] = mk_key(e[j], a);
                } else if (e[j] == cut) {
                    int p = atomicAdd(&s_nTie, 1);
                    tieIdx[p] = a;
                }
            }
        }
    }
    __syncthreads();
    int m = s_nHigh;
    int nt = s_nTie;

    if (t < 128) finalKeys[t] = 0ull;
    __syncthreads();
    if (t < m) finalKeys[t] = highKeys[t];

    if (nt == r) {
        if (t < nt) finalKeys[m + t] = mk_key(cut, tieIdx[t]);
        __syncthreads();
    } else {
        __syncthreads();
        for (int j = 0; j < r; ++j) {
            int mn = 0x7FFFFFFF;
            for (int p = t; p < nt; p += 256) mn = min(mn, tieIdx[p]);
            for (int off = 32; off > 0; off >>= 1) mn = min(mn, __shfl_down(mn, off, 64));
            if (lane == 0) wmin[wv] = mn;
            __syncthreads();
            if (t == 0) {
                int v = min(min(wmin[0], wmin[1]), min(wmin[2], wmin[3]));
                s_bcast = v;
                finalKeys[m + j] = mk_key(cut, v);
            }
            __syncthreads();
            int v = s_bcast;
            for (int p = t; p < nt; p += 256)
                if (tieIdx[p] == v) tieIdx[p] = 0x7FFFFFFF;
            __syncthreads();
        }
    }

    for (int ksz = 2; ksz <= 128; ksz <<= 1) {
        for (int j = ksz >> 1; j > 0; j >>= 1) {
            if (t < 128) {
                int ixj = t ^ j;
                if (ixj > t) {
                    bool desc = ((t & ksz) == 0);
                    unsigned long long x = finalKeys[t], y = finalKeys[ixj];
                    bool sw = desc ? (x < y) : (x > y);
                    if (sw) { finalKeys[t] = y; finalKeys[ixj] = x; }
                }
            }
            __syncthreads();
        }
    }

    if (t < MAX_DET) {
        unsigned long long kk = finalKeys[t];
        float sc = __uint_as_float((unsigned)(kk >> 32));
        int a = 0x7FFFFFFF - (int)(kk & 0xFFFFFFFFull);
        out[OUT_SCORE + b * MAX_DET + t] = sc;
        out[OUT_CLASS + b * MAX_DET + t] = (float)cls_id[b * A_TOT + a];
        top_idx[b * MAX_DET + t] = a;
        if (sc > 0.25f) atomicAdd(&s_cnt, 1);
    }
    __syncthreads();
    if (t == 0) out[OUT_NUM + b] = (float)s_cnt;
}

// -------- Kernel 3: decode box + kpts for selected anchors (float4 dot) --------
__global__ __launch_bounds__(128) void decode_kernel(
    const float* __restrict__ x0, const float* __restrict__ x1, const float* __restrict__ x2,
    const float* __restrict__ w2_0, const float* __restrict__ b2_0,
    const float* __restrict__ w2_1, const float* __restrict__ b2_1,
    const float* __restrict__ w2_2, const float* __restrict__ b2_2,
    const float* __restrict__ w4_0, const float* __restrict__ b4_0,
    const float* __restrict__ w4_1, const float* __restrict__ b4_1,
    const float* __restrict__ w4_2, const float* __restrict__ b4_2,
    const int* __restrict__ top_idx,
    float* __restrict__ out)
{
    int b = blockIdx.y;
    int k = blockIdx.x;
    int a = top_idx[b * MAX_DET + k];

    const float* x; const float* w2; const float* bb2; const float* w4; const float* bb4;
    int C, A, W, a_local; float stride;
    if (a < 6400)      { x = x0; C = 128; A = 6400; W = 80; stride = 8.0f;  a_local = a;        w2 = w2_0; bb2 = b2_0; w4 = w4_0; bb4 = b4_0; }
    else if (a < 8000) { x = x1; C = 256; A = 1600; W = 40; stride = 16.0f; a_local = a - 6400; w2 = w2_1; bb2 = b2_1; w4 = w4_1; bb4 = b4_1; }
    else               { x = x2; C = 512; A = 400;  W = 20; stride = 32.0f; a_local = a - 8000; w2 = w2_2; bb2 = b2_2; w4 = w4_2; bb4 = b4_2; }

    __shared__ float fs[512];
    __shared__ float logits[64];
    __shared__ float kraw[NK];
    __shared__ float dist[4];

    int t = threadIdx.x;
    for (int c = t; c < C; c += 128)
        fs[c] = x[((long)b * C + c) * A + a_local];
    __syncthreads();

    if (t < 64 + NK) {
        const float* wrow; float acc;
        if (t < 64) { wrow = w2 + t * C; acc = bb2[t]; }
        else        { wrow = w4 + (t - 64) * C; acc = bb4[t - 64]; }
        for (int c = 0; c < C; c += 4) {
            float4 wv4 = *(const float4*)(wrow + c);
            float4 fv4 = *(const float4*)(&fs[c]);
            acc = fmaf(wv4.x, fv4.x, acc);
            acc = fmaf(wv4.y, fv4.y, acc);
            acc = fmaf(wv4.z, fv4.z, acc);
            acc = fmaf(wv4.w, fv4.w, acc);
        }
        if (t < 64) logits[t] = acc;
        else        kraw[t - 64] = acc;
    }
    __syncthreads();

    if (t < 4) {
        float mx = logits[t * 16];
#pragma unroll
        for (int r = 1; r < 16; ++r) mx = fmaxf(mx, logits[t * 16 + r]);
        float se = 0.0f, sw = 0.0f;
#pragma unroll
        for (int r = 0; r < 16; ++r) {
            float e = expf(logits[t * 16 + r] - mx);
            se += e; sw += e * (float)r;
        }
        dist[t] = sw / se;
    }
    __syncthreads();

    float ax = (float)(a_local % W) + 0.5f;
    float ay = (float)(a_local / W) + 0.5f;

    if (t == 0) {
        float x1c = ax - dist[0], y1c = ay - dist[1];
        float x2c = ax + dist[2], y2c = ay + dist[3];
        float* ob = out + OUT_BOX + ((long)b * MAX_DET + k) * 4;
        ob[0] = (x1c + x2c) * 0.5f * stride;
        ob[1] = (y1c + y2c) * 0.5f * stride;
        ob[2] = (x2c - x1c) * stride;
        ob[3] = (y2c - y1c) * stride;
    }
    if (t < 17) {
        float vx = kraw[t * 3], vy = kraw[t * 3 + 1], vv = kraw[t * 3 + 2];
        float gx = ax - 0.5f, gy = ay - 0.5f;
        float* ok = out + OUT_KPT + (((long)b * MAX_DET + k) * 17 + t) * 3;
        ok[0] = (vx * 2.0f + gx) * stride;
        ok[1] = (vy * 2.0f + gy) * stride;
        ok[2] = 1.0f / (1.0f + expf(-vv));
    }
}

extern "C" void kernel_launch(void* const* d_in, const int* in_sizes, int n_in,
                              void* d_out, int out_size, void* d_ws, size_t ws_size,
                              hipStream_t stream) {
    const float* x0 = (const float*)d_in[0];
    const float* x1 = (const float*)d_in[1];
    const float* x2 = (const float*)d_in[2];
    const float* w2[3] = {(const float*)d_in[3], (const float*)d_in[5], (const float*)d_in[7]};
    const float* b2[3] = {(const float*)d_in[4], (const float*)d_in[6], (const float*)d_in[8]};
    const float* w3[3] = {(const float*)d_in[9], (const float*)d_in[11], (const float*)d_in[13]};
    const float* b3[3] = {(const float*)d_in[10], (const float*)d_in[12], (const float*)d_in[14]};
    const float* w4[3] = {(const float*)d_in[15], (const float*)d_in[17], (const float*)d_in[19]};
    const float* b4[3] = {(const float*)d_in[16], (const float*)d_in[18], (const float*)d_in[20]};

    float* out = (float*)d_out;

    float* ws_maxs = (float*)d_ws;                    // [16][8400]
    int* ws_cls = (int*)(ws_maxs + BS * A_TOT);       // [16][8400]
    int* ws_top = (int*)(ws_cls + BS * A_TOT);        // [16][100]

    // fused scores: 32 (L2) + 112 (L1) + 400 (L0) blocks of 256 threads
    scores_fused<<<dim3(544), 256, 0, stream>>>(
        x0, x1, x2, w3[0], w3[1], w3[2], b3[0], b3[1], b3[2], ws_maxs, ws_cls);
    topk_kernel<<<dim3(BS), 256, 0, stream>>>(ws_maxs, ws_cls, out, ws_top);
    decode_kernel<<<dim3(MAX_DET, BS), 128, 0, stream>>>(
        x0, x1, x2,
        w2[0], b2[0], w2[1], b2[1], w2[2], b2[2],
        w4[0], b4[0], w4[1], b4[1], w4[2], b4[2],
        ws_top, out);
}

// Round 12
// 303.335 us; speedup vs baseline: 4.0039x; 1.0265x over previous
//
#include <hip/hip_runtime.h>
#include <hip/hip_bf16.h>

#define NC 80
#define NK 51
#define REG_MAX 16
#define MAX_DET 100
#define A_TOT 8400
#define BS 16

// out layout (float32): num[16] | boxes[16*100*4] | scores[16*100] | classes[16*100] | kpts[16*100*17*3]
#define OUT_NUM 0
#define OUT_BOX 16
#define OUT_SCORE (16 + 16*MAX_DET*4)
#define OUT_CLASS (OUT_SCORE + 16*MAX_DET)
#define OUT_KPT (OUT_CLASS + 16*MAX_DET)

static __device__ __forceinline__ unsigned long long mk_key(unsigned u, int a) {
    return ((unsigned long long)u << 32) | (unsigned)(0x7FFFFFFF - a);
}

// -------- Kernel 1 v11: v10 compute structure + oc-split work balance --------
// v10 diagnosis: OccupancyPercent 8% = tail signature. L2 blocks were 4
// units of serial work; after L0/L1 drain, 32 blocks run alone on 32 CUs
// for ~half the kernel. Fix (verified machinery from v7/v9): split L2
// into 4 oc-quarters (20 ocs) and L1 into 2 oc-halves (40 ocs) -> 752
// equal 1-unit blocks (~2.9/CU), topk merges partials (ascending group,
// strict > => first-max). Group 0 writes max_s directly; groups>=1 write
// workspace partials. Compute structure is v10 verbatim: PP=4, feature
// ds_read_b128, weight broadcast, 2 barriers/chunk, bias + strictly
// ascending channel fmaf chain -> every candidate bit-identical.
template<int C, int NOC>
static __device__ __forceinline__ void score_tile(
    const float* __restrict__ x, const float* __restrict__ w,
    const float* __restrict__ bias,
    int b, int a0, int oc_base, int A,
    float* __restrict__ out_m, int* __restrict__ out_i,
    float* __restrict__ fs, float* __restrict__ wsh,
    float (*rm)[256], int (*ri)[256])
{
    constexpr int O = NOC / 4;       // ocs per wave
    constexpr int NF4 = NOC * 8;     // float4 per weight chunk

    int t = threadIdx.x;
    int lane = t & 63;
    int wv = t >> 6;
    int oc0 = wv * O;                // block-local first oc for this wave

    float acc[O][4];
#pragma unroll
    for (int j = 0; j < O; ++j) {
        float bv = bias[oc_base + oc0 + j];
        acc[j][0] = bv; acc[j][1] = bv; acc[j][2] = bv; acc[j][3] = bv;
    }

    const float* xb = x + (long)b * C * A;
    constexpr int nchunk = C >> 5;

    for (int kc = 0; kc < nchunk; ++kc) {
        __syncthreads();
        // stage features: 32 channels x 256 anchors = 2048 float4 (8/thread)
#pragma unroll
        for (int i = 0; i < 8; ++i) {
            int idx = t + i * 256;
            int c = idx >> 6;
            int q = (idx & 63) * 4;
            int aa = a0 + q; if (aa > A - 4) aa = A - 4;   // ragged: dup, writes guarded
            float4 v = *(const float4*)(xb + (long)(kc * 32 + c) * A + aa);
            *(float4*)(&fs[c * 256 + q]) = v;
        }
        // stage weights: NOC ocs x 32 channels = NOC*8 float4
#pragma unroll
        for (int i = 0; i < 3; ++i) {
            int idx = t + i * 256;
            if (idx < NF4) {
                int oc = idx >> 3;
                int q = (idx & 7) * 4;
                float4 v = *(const float4*)(w + (long)(oc_base + oc) * C + kc * 32 + q);
                *(float4*)(&wsh[oc * 32 + q]) = v;
            }
        }
        __syncthreads();

#pragma unroll 1
        for (int c4 = 0; c4 < 32; c4 += 4) {
            // 4 consecutive anchors per lane -> one ds_read_b128 per channel
            float4 f[4];
#pragma unroll
            for (int cc = 0; cc < 4; ++cc)
                f[cc] = *(const float4*)(&fs[(c4 + cc) * 256 + lane * 4]);
#pragma unroll
            for (int j = 0; j < O; ++j) {
                float4 w4 = *(const float4*)(&wsh[(oc0 + j) * 32 + c4]);  // broadcast
                // ascending-channel chain per (oc, anchor) - bit-identical
                acc[j][0] = fmaf(w4.x, f[0].x, acc[j][0]);
                acc[j][0] = fmaf(w4.y, f[1].x, acc[j][0]);
                acc[j][0] = fmaf(w4.z, f[2].x, acc[j][0]);
                acc[j][0] = fmaf(w4.w, f[3].x, acc[j][0]);
                acc[j][1] = fmaf(w4.x, f[0].y, acc[j][1]);
                acc[j][1] = fmaf(w4.y, f[1].y, acc[j][1]);
                acc[j][1] = fmaf(w4.z, f[2].y, acc[j][1]);
                acc[j][1] = fmaf(w4.w, f[3].y, acc[j][1]);
                acc[j][2] = fmaf(w4.x, f[0].z, acc[j][2]);
                acc[j][2] = fmaf(w4.y, f[1].z, acc[j][2]);
                acc[j][2] = fmaf(w4.z, f[2].z, acc[j][2]);
                acc[j][2] = fmaf(w4.w, f[3].z, acc[j][2]);
                acc[j][3] = fmaf(w4.x, f[0].w, acc[j][3]);
                acc[j][3] = fmaf(w4.y, f[1].w, acc[j][3]);
                acc[j][3] = fmaf(w4.z, f[2].w, acc[j][3]);
                acc[j][3] = fmaf(w4.w, f[3].w, acc[j][3]);
            }
        }
    }

    // per-anchor argmax over this thread's O ocs (first-max semantics)
#pragma unroll
    for (int q = 0; q < 4; ++q) {
        float m = acc[0][q]; int mi = 0;
#pragma unroll
        for (int j = 1; j < O; ++j)
            if (acc[j][q] > m) { m = acc[j][q]; mi = j; }
        rm[wv][lane * 4 + q] = m;
        ri[wv][lane * 4 + q] = oc_base + oc0 + mi;
    }
    __syncthreads();

    // cross-wave reduce: ascending wv = ascending oc keeps first-max
    {
        float bm = rm[0][t]; int bi = ri[0][t];
#pragma unroll
        for (int v = 1; v < 4; ++v) {
            float om = rm[v][t];
            if (om > bm) { bm = om; bi = ri[v][t]; }
        }
        int ga = a0 + t;
        if (ga < A) {
            out_m[ga] = 1.0f / (1.0f + expf(-bm));
            out_i[ga] = bi;
        }
    }
}

__global__ __launch_bounds__(256) void scores_fused(
    const float* __restrict__ x0, const float* __restrict__ x1, const float* __restrict__ x2,
    const float* __restrict__ w0, const float* __restrict__ w1, const float* __restrict__ w2,
    const float* __restrict__ bias0, const float* __restrict__ bias1, const float* __restrict__ bias2,
    float* __restrict__ max_s,       // [BS][A_TOT]  (group-0 candidates)
    int* __restrict__ cls_id,
    float* __restrict__ l1m, int* __restrict__ l1i,   // [1][BS][1600] (group 1)
    float* __restrict__ l2m, int* __restrict__ l2i)   // [3][BS][400]  (groups 1..3)
{
    __shared__ float fs[32 * 256];   // 32 KB  [c][a]
    __shared__ float wsh[80 * 32];   // 10 KB  [oc][c] (max NOC=80)
    __shared__ float rm[4][256];
    __shared__ int   ri[4][256];

    int bid = blockIdx.x;
    if (bid < 128) {                 // L2: 16 b x 2 tiles x 4 oc-quarters
        int b = bid >> 3, rem = bid & 7;
        int tile = rem >> 2, g = rem & 3;
        float* om; int* oi;
        if (g == 0) { om = max_s + (long)b * A_TOT + 8000; oi = cls_id + (long)b * A_TOT + 8000; }
        else        { om = l2m + ((long)(g - 1) * BS + b) * 400; oi = l2i + ((long)(g - 1) * BS + b) * 400; }
        score_tile<512, 20>(x2, w2, bias2, b, tile * 256, g * 20, 400, om, oi, fs, wsh, rm, ri);
    } else if (bid < 352) {          // L1: 16 b x 7 tiles x 2 oc-halves
        int r = bid - 128;
        int b = r / 14, rem = r - b * 14;
        int tile = rem >> 1, g = rem & 1;
        float* om; int* oi;
        if (g == 0) { om = max_s + (long)b * A_TOT + 6400; oi = cls_id + (long)b * A_TOT + 6400; }
        else        { om = l1m + (long)b * 1600; oi = l1i + (long)b * 1600; }
        score_tile<256, 40>(x1, w1, bias1, b, tile * 256, g * 40, 1600, om, oi, fs, wsh, rm, ri);
    } else {                         // L0: 16 b x 25 tiles, full 80 ocs
        int r = bid - 352;
        int b = r / 25, tile = r - b * 25;
        score_tile<128, 80>(x0, w0, bias0, b, tile * 256, 0, 6400,
            max_s + (long)b * A_TOT, cls_id + (long)b * A_TOT, fs, wsh, rm, ri);
    }
}

// -------- Kernel 2: merge partials + exact top-100 radix select --------
__global__ __launch_bounds__(256) void topk_kernel(
    float* __restrict__ max_s,       // [BS][A_TOT] (L1/L2 regions merged here)
    int* __restrict__ cls_id,
    const float* __restrict__ l1m, const int* __restrict__ l1i,
    const float* __restrict__ l2m, const int* __restrict__ l2i,
    float* __restrict__ out,
    int* __restrict__ top_idx)       // [BS][MAX_DET]
{
    int b = blockIdx.x;
    int t = threadIdx.x;
    int lane = t & 63;
    int wv = t >> 6;

    // merge oc-group partials (ascending group, strict > => first-max over oc)
    for (int a = t; a < 1600; a += 256) {
        float bs_ = max_s[(long)b * A_TOT + 6400 + a];
        int   bi_ = cls_id[(long)b * A_TOT + 6400 + a];
        float s1 = l1m[(long)b * 1600 + a];
        if (s1 > bs_) { bs_ = s1; bi_ = l1i[(long)b * 1600 + a]; }
        max_s[(long)b * A_TOT + 6400 + a] = bs_;
        cls_id[(long)b * A_TOT + 6400 + a] = bi_;
    }
    for (int a = t; a < 400; a += 256) {
        float bs_ = max_s[(long)b * A_TOT + 8000 + a];
        int   bi_ = cls_id[(long)b * A_TOT + 8000 + a];
#pragma unroll
        for (int g = 0; g < 3; ++g) {
            float s = l2m[((long)g * BS + b) * 400 + a];
            if (s > bs_) { bs_ = s; bi_ = l2i[((long)g * BS + b) * 400 + a]; }
        }
        max_s[(long)b * A_TOT + 8000 + a] = bs_;
        cls_id[(long)b * A_TOT + 8000 + a] = bi_;
    }
    __syncthreads();

    __shared__ unsigned hist[4 * 256];
    __shared__ int tieIdx[A_TOT];
    __shared__ unsigned long long highKeys[128];
    __shared__ unsigned long long finalKeys[128];
    __shared__ int wmin[4];
    __shared__ unsigned s_prefix;
    __shared__ int s_k, s_nHigh, s_nTie, s_cnt, s_bcast;

    uint4 uu[9];
#pragma unroll
    for (int i = 0; i < 9; ++i) {
        int idx = t + i * 256;
        if (i < 8 || t < 52)
            uu[i] = *(const uint4*)((const unsigned*)(max_s + (long)b * A_TOT) + idx * 4);
        else
            uu[i] = make_uint4(0u, 0u, 0u, 0u);
    }

    if (t == 0) { s_prefix = 0; s_k = MAX_DET; s_nHigh = 0; s_nTie = 0; s_cnt = 0; }

    for (int pass = 0; pass < 4; ++pass) {
#pragma unroll
        for (int j = 0; j < 4; ++j) hist[t + j * 256] = 0;
        __syncthreads();

        unsigned pre = s_prefix;
        int k = s_k;
        int shHi = 32 - 8 * pass;
        int shD = 24 - 8 * pass;
#pragma unroll
        for (int i = 0; i < 9; ++i) {
            if (i < 8 || t < 52) {
                unsigned e[4] = { uu[i].x, uu[i].y, uu[i].z, uu[i].w };
#pragma unroll
                for (int j = 0; j < 4; ++j) {
                    bool cand = (pass == 0) ? true : ((e[j] >> shHi) == pre);
                    if (cand)
                        atomicAdd(&hist[(wv << 8) + ((e[j] >> shD) & 0xFF)], 1u);
                }
            }
        }
        __syncthreads();

        if (wv == 0) {
            unsigned c0 = 0, c1 = 0, c2 = 0, c3 = 0;
#pragma unroll
            for (int w = 0; w < 4; ++w) {
                const unsigned* hp = &hist[(w << 8) + lane * 4];
                c0 += hp[0]; c1 += hp[1]; c2 += hp[2]; c3 += hp[3];
            }
            unsigned s3 = c3, s2 = c2 + s3, s1 = c1 + s2, s0 = c0 + s1;
            unsigned tsum = s0;
#pragma unroll
            for (int off = 1; off < 64; off <<= 1) {
                unsigned o = __shfl_down(tsum, off, 64);
                if (lane + off < 64) tsum += o;
            }
            unsigned excl = tsum - s0;
            unsigned S0 = excl + s0, S1 = excl + s1, S2 = excl + s2, S3 = excl + s3;
            int ld = -1;
            unsigned uk = (unsigned)k;
            if (S3 >= uk)      ld = lane * 4 + 3;
            else if (S2 >= uk) ld = lane * 4 + 2;
            else if (S1 >= uk) ld = lane * 4 + 1;
            else if (S0 >= uk) ld = lane * 4 + 0;
            int d = ld;
#pragma unroll
            for (int off = 32; off > 0; off >>= 1) d = max(d, __shfl_xor(d, off, 64));
            int dn = d + 1;
            unsigned mine = 0;
            if (dn < 256 && lane == (dn >> 2)) {
                int e = dn & 3;
                mine = (e == 0) ? S0 : (e == 1) ? S1 : (e == 2) ? S2 : S3;
            }
#pragma unroll
            for (int off = 32; off > 0; off >>= 1) mine += __shfl_xor(mine, off, 64);
            if (lane == 0) {
                s_k = k - (int)mine;
                s_prefix = (pre << 8) | (unsigned)d;
            }
        }
        __syncthreads();
    }

    unsigned cut = s_prefix;
    int r = s_k;

#pragma unroll
    for (int i = 0; i < 9; ++i) {
        if (i < 8 || t < 52) {
            unsigned e[4] = { uu[i].x, uu[i].y, uu[i].z, uu[i].w };
#pragma unroll
            for (int j = 0; j < 4; ++j) {
                int a = (t + i * 256) * 4 + j;
                if (e[j] > cut) {
                    int p = atomicAdd(&s_nHigh, 1);
                    highKeys[p] = mk_key(e[j], a);
                } else if (e[j] == cut) {
                    int p = atomicAdd(&s_nTie, 1);
                    tieIdx[p] = a;
                }
            }
        }
    }
    __syncthreads();
    int m = s_nHigh;
    int nt = s_nTie;

    if (t < 128) finalKeys[t] = 0ull;
    __syncthreads();
    if (t < m) finalKeys[t] = highKeys[t];

    if (nt == r) {
        if (t < nt) finalKeys[m + t] = mk_key(cut, tieIdx[t]);
        __syncthreads();
    } else {
        __syncthreads();
        for (int j = 0; j < r; ++j) {
            int mn = 0x7FFFFFFF;
            for (int p = t; p < nt; p += 256) mn = min(mn, tieIdx[p]);
            for (int off = 32; off > 0; off >>= 1) mn = min(mn, __shfl_down(mn, off, 64));
            if (lane == 0) wmin[wv] = mn;
            __syncthreads();
            if (t == 0) {
                int v = min(min(wmin[0], wmin[1]), min(wmin[2], wmin[3]));
                s_bcast = v;
                finalKeys[m + j] = mk_key(cut, v);
            }
            __syncthreads();
            int v = s_bcast;
            for (int p = t; p < nt; p += 256)
                if (tieIdx[p] == v) tieIdx[p] = 0x7FFFFFFF;
            __syncthreads();
        }
    }

    for (int ksz = 2; ksz <= 128; ksz <<= 1) {
        for (int j = ksz >> 1; j > 0; j >>= 1) {
            if (t < 128) {
                int ixj = t ^ j;
                if (ixj > t) {
                    bool desc = ((t & ksz) == 0);
                    unsigned long long x = finalKeys[t], y = finalKeys[ixj];
                    bool sw = desc ? (x < y) : (x > y);
                    if (sw) { finalKeys[t] = y; finalKeys[ixj] = x; }
                }
            }
            __syncthreads();
        }
    }

    if (t < MAX_DET) {
        unsigned long long kk = finalKeys[t];
        float sc = __uint_as_float((unsigned)(kk >> 32));
        int a = 0x7FFFFFFF - (int)(kk & 0xFFFFFFFFull);
        out[OUT_SCORE + b * MAX_DET + t] = sc;
        out[OUT_CLASS + b * MAX_DET + t] = (float)cls_id[b * A_TOT + a];
        top_idx[b * MAX_DET + t] = a;
        if (sc > 0.25f) atomicAdd(&s_cnt, 1);
    }
    __syncthreads();
    if (t == 0) out[OUT_NUM + b] = (float)s_cnt;
}

// -------- Kernel 3: decode box + kpts for selected anchors (float4 dot) --------
__global__ __launch_bounds__(128) void decode_kernel(
    const float* __restrict__ x0, const float* __restrict__ x1, const float* __restrict__ x2,
    const float* __restrict__ w2_0, const float* __restrict__ b2_0,
    const float* __restrict__ w2_1, const float* __restrict__ b2_1,
    const float* __restrict__ w2_2, const float* __restrict__ b2_2,
    const float* __restrict__ w4_0, const float* __restrict__ b4_0,
    const float* __restrict__ w4_1, const float* __restrict__ b4_1,
    const float* __restrict__ w4_2, const float* __restrict__ b4_2,
    const int* __restrict__ top_idx,
    float* __restrict__ out)
{
    int b = blockIdx.y;
    int k = blockIdx.x;
    int a = top_idx[b * MAX_DET + k];

    const float* x; const float* w2; const float* bb2; const float* w4; const float* bb4;
    int C, A, W, a_local; float stride;
    if (a < 6400)      { x = x0; C = 128; A = 6400; W = 80; stride = 8.0f;  a_local = a;        w2 = w2_0; bb2 = b2_0; w4 = w4_0; bb4 = b4_0; }
    else if (a < 8000) { x = x1; C = 256; A = 1600; W = 40; stride = 16.0f; a_local = a - 6400; w2 = w2_1; bb2 = b2_1; w4 = w4_1; bb4 = b4_1; }
    else               { x = x2; C = 512; A = 400;  W = 20; stride = 32.0f; a_local = a - 8000; w2 = w2_2; bb2 = b2_2; w4 = w4_2; bb4 = b4_2; }

    __shared__ float fs[512];
    __shared__ float logits[64];
    __shared__ float kraw[NK];
    __shared__ float dist[4];

    int t = threadIdx.x;
    for (int c = t; c < C; c += 128)
        fs[c] = x[((long)b * C + c) * A + a_local];
    __syncthreads();

    if (t < 64 + NK) {
        const float* wrow; float acc;
        if (t < 64) { wrow = w2 + t * C; acc = bb2[t]; }
        else        { wrow = w4 + (t - 64) * C; acc = bb4[t - 64]; }
        for (int c = 0; c < C; c += 4) {
            float4 wv4 = *(const float4*)(wrow + c);
            float4 fv4 = *(const float4*)(&fs[c]);
            acc = fmaf(wv4.x, fv4.x, acc);
            acc = fmaf(wv4.y, fv4.y, acc);
            acc = fmaf(wv4.z, fv4.z, acc);
            acc = fmaf(wv4.w, fv4.w, acc);
        }
        if (t < 64) logits[t] = acc;
        else        kraw[t - 64] = acc;
    }
    __syncthreads();

    if (t < 4) {
        float mx = logits[t * 16];
#pragma unroll
        for (int r = 1; r < 16; ++r) mx = fmaxf(mx, logits[t * 16 + r]);
        float se = 0.0f, sw = 0.0f;
#pragma unroll
        for (int r = 0; r < 16; ++r) {
            float e = expf(logits[t * 16 + r] - mx);
            se += e; sw += e * (float)r;
        }
        dist[t] = sw / se;
    }
    __syncthreads();

    float ax = (float)(a_local % W) + 0.5f;
    float ay = (float)(a_local / W) + 0.5f;

    if (t == 0) {
        float x1c = ax - dist[0], y1c = ay - dist[1];
        float x2c = ax + dist[2], y2c = ay + dist[3];
        float* ob = out + OUT_BOX + ((long)b * MAX_DET + k) * 4;
        ob[0] = (x1c + x2c) * 0.5f * stride;
        ob[1] = (y1c + y2c) * 0.5f * stride;
        ob[2] = (x2c - x1c) * stride;
        ob[3] = (y2c - y1c) * stride;
    }
    if (t < 17) {
        float vx = kraw[t * 3], vy = kraw[t * 3 + 1], vv = kraw[t * 3 + 2];
        float gx = ax - 0.5f, gy = ay - 0.5f;
        float* ok = out + OUT_KPT + (((long)b * MAX_DET + k) * 17 + t) * 3;
        ok[0] = (vx * 2.0f + gx) * stride;
        ok[1] = (vy * 2.0f + gy) * stride;
        ok[2] = 1.0f / (1.0f + expf(-vv));
    }
}

extern "C" void kernel_launch(void* const* d_in, const int* in_sizes, int n_in,
                              void* d_out, int out_size, void* d_ws, size_t ws_size,
                              hipStream_t stream) {
    const float* x0 = (const float*)d_in[0];
    const float* x1 = (const float*)d_in[1];
    const float* x2 = (const float*)d_in[2];
    const float* w2[3] = {(const float*)d_in[3], (const float*)d_in[5], (const float*)d_in[7]};
    const float* b2[3] = {(const float*)d_in[4], (const float*)d_in[6], (const float*)d_in[8]};
    const float* w3[3] = {(const float*)d_in[9], (const float*)d_in[11], (const float*)d_in[13]};
    const float* b3[3] = {(const float*)d_in[10], (const float*)d_in[12], (const float*)d_in[14]};
    const float* w4[3] = {(const float*)d_in[15], (const float*)d_in[17], (const float*)d_in[19]};
    const float* b4[3] = {(const float*)d_in[16], (const float*)d_in[18], (const float*)d_in[20]};

    float* out = (float*)d_out;

    float* ws_maxs = (float*)d_ws;                     // [16][8400]
    int*   ws_cls  = (int*)(ws_maxs + BS * A_TOT);     // [16][8400]
    int*   ws_top  = (int*)(ws_cls + BS * A_TOT);      // [16][100]
    float* ws_l1m  = (float*)(ws_top + BS * MAX_DET);  // [16][1600]
    int*   ws_l1i  = (int*)(ws_l1m + BS * 1600);       // [16][1600]
    float* ws_l2m  = (float*)(ws_l1i + BS * 1600);     // [3][16][400]
    int*   ws_l2i  = (int*)(ws_l2m + 3 * BS * 400);    // [3][16][400]

    // 128 (L2 quarters) + 224 (L1 halves) + 400 (L0) = 752 blocks
    scores_fused<<<dim3(752), 256, 0, stream>>>(
        x0, x1, x2, w3[0], w3[1], w3[2], b3[0], b3[1], b3[2],
        ws_maxs, ws_cls, ws_l1m, ws_l1i, ws_l2m, ws_l2i);
    topk_kernel<<<dim3(BS), 256, 0, stream>>>(
        ws_maxs, ws_cls, ws_l1m, ws_l1i, ws_l2m, ws_l2i, out, ws_top);
    decode_kernel<<<dim3(MAX_DET, BS), 128, 0, stream>>>(
        x0, x1, x2,
        w2[0], b2[0], w2[1], b2[1], w2[2], b2[2],
        w4[0], b4[0], w4[1], b4[1], w4[2], b4[2],
        ws_top, out);
}